// Round 12
// baseline (90.931 us; speedup 1.0000x reference)
//
#include <hip/hip_runtime.h>

typedef _Float16 half_t;
typedef _Float16 halfv8 __attribute__((ext_vector_type(8)));
typedef _Float16 halfv4 __attribute__((ext_vector_type(4)));
typedef float    floatv4 __attribute__((ext_vector_type(4)));
typedef unsigned int uint;
typedef uint uintv4 __attribute__((ext_vector_type(4)));

#define NODES 32
#define FIN   128
#define EPG   512
#define NBS   4096
#define ETOT  (NBS*EPG)
#define HID   1024
#define KDIM  4096          // FIN*NODES
#define NCLS  10
#define YP    36            // pitch (halves) for Z^T / H^T bounce
#define WP    140           // pitch (halves) for W in LDS

// lin1 GEMM geometry (half-tile pipelined, audited r7 schedule)
#define BM 256
#define BN 256
#define BK 64
#define KS 4
#define KSLEN (KDIM/KS)  // 1024
#define NT (KSLEN/BK)    // 16 K-tiles

#define GLDS16(g, l)                                                        \
  __builtin_amdgcn_global_load_lds(                                         \
      (const __attribute__((address_space(1))) unsigned int*)(g),           \
      (__attribute__((address_space(3))) unsigned int*)(l), 16, 0, 0)

// ---------------------------------------------------------------------------
// prep: pure fp32->fp16 casts (H layout [g][o*32+m] matches original w1).
__global__ __launch_bounds__(256) void prep_cvt(const float* __restrict__ w1,
                                                half_t* __restrict__ w1p,
                                                const float* __restrict__ gw,
                                                half_t* __restrict__ gw16) {
  const size_t q = (size_t)blockIdx.x * 256 + threadIdx.x;  // 1052672 quads
  const float* s;
  half_t* d;
  size_t off;
  if (q < 1048576) { s = w1; d = w1p; off = q; }
  else             { s = gw; d = gw16; off = q - 1048576; }
  floatv4 v = *(const floatv4*)(s + off * 4);
  halfv4 h = {(half_t)v[0], (half_t)v[1], (half_t)v[2], (half_t)v[3]};
  *(halfv4*)(d + off * 4) = h;
}

// ---------------------------------------------------------------------------
// gin_fused v6 (r10/r11, proven, UNCHANGED): W block-staged in LDS;
// Z^T/H^T LDS bounce; fat coalesced H stores.
__global__ __launch_bounds__(256, 2) void gin_fused(
    const float* __restrict__ x, const int* __restrict__ ei,
    const half_t* __restrict__ gw16, const float* __restrict__ gb,
    half_t* __restrict__ H) {
  __shared__ __attribute__((aligned(16))) half_t Ws[FIN * WP];     // 35840 B
  __shared__ __attribute__((aligned(16))) half_t Yt[4][FIN * YP];  // 36864 B
  __shared__ uint cnt[4][512];                                     //  8192 B

  const int t = threadIdx.x, w = t >> 6, l = t & 63;
  const int lr = l & 15, lk = l >> 4;
  const int g = blockIdx.x * 4 + w;

  const float* xg = x + (size_t)g * (NODES * FIN);
  floatv4 xr[2][4][2];
#pragma unroll
  for (int mt = 0; mt < 2; ++mt)
#pragma unroll
    for (int kk = 0; kk < 4; ++kk) {
      const float* p = xg + (mt * 16 + lr) * FIN + kk * 32 + lk * 8;
      xr[mt][kk][0] = *(const floatv4*)p;
      xr[mt][kk][1] = *(const floatv4*)(p + 4);
    }

  {
    const halfv8* gsrc = (const halfv8*)gw16;
#pragma unroll
    for (int i = 0; i < 8; ++i) {
      const int c = i * 256 + t;
      const int o = c >> 4, f8 = c & 15;
      *(halfv8*)&Ws[o * WP + f8 * 8] = gsrc[c];
    }
  }

  const int* sp = ei + (size_t)g * EPG;
  const int* dp = ei + (size_t)ETOT + (size_t)g * EPG;
  uintv4 s0 = *(const uintv4*)(sp + l * 8);
  uintv4 s1 = *(const uintv4*)(sp + l * 8 + 4);
  uintv4 d0 = *(const uintv4*)(dp + l * 8);
  uintv4 d1 = *(const uintv4*)(dp + l * 8 + 4);

  {
    uintv4* c4 = (uintv4*)cnt[w];
    uintv4 z = {0, 0, 0, 0};
    c4[l] = z;
    c4[l + 64] = z;
  }
#pragma unroll
  for (int q = 0; q < 4; ++q) {
    uint p0 = (d0[q] & 31) * 32 + (s0[q] & 31);
    atomicAdd(&cnt[w][p0 >> 1], 1u << ((p0 & 1) * 16));
    uint p1 = (d1[q] & 31) * 32 + (s1[q] & 31);
    atomicAdd(&cnt[w][p1 >> 1], 1u << ((p1 & 1) * 16));
  }

  halfv8 af[2][4];
#pragma unroll
  for (int mt = 0; mt < 2; ++mt)
#pragma unroll
    for (int kk = 0; kk < 4; ++kk) {
      halfv8 h;
#pragma unroll
      for (int q = 0; q < 4; ++q) {
        h[q]     = (half_t)xr[mt][kk][0][q];
        h[q + 4] = (half_t)xr[mt][kk][1][q];
      }
      af[mt][kk] = h;
    }

  __syncthreads();   // Ws staged (cross-wave)

  floatv4 acc[2][8] = {};
#pragma unroll
  for (int kk = 0; kk < 4; ++kk) {
    halfv8 bfk[8];
#pragma unroll
    for (int nt = 0; nt < 8; ++nt)
      bfk[nt] = *(const halfv8*)&Ws[(nt * 16 + lr) * WP + kk * 32 + lk * 8];
#pragma unroll
    for (int nt = 0; nt < 8; ++nt)
#pragma unroll
      for (int mt = 0; mt < 2; ++mt)
        acc[mt][nt] = __builtin_amdgcn_mfma_f32_16x16x32_f16(af[mt][kk], bfk[nt],
                                                             acc[mt][nt], 0, 0, 0);
  }
  __builtin_amdgcn_sched_barrier(0);

  half_t* yw = Yt[w];
#pragma unroll
  for (int mt = 0; mt < 2; ++mt)
#pragma unroll
    for (int nt = 0; nt < 8; ++nt) {
      halfv4 h = {(half_t)acc[mt][nt][0], (half_t)acc[mt][nt][1],
                  (half_t)acc[mt][nt][2], (half_t)acc[mt][nt][3]};
      *(halfv4*)&yw[(nt * 16 + lr) * YP + mt * 16 + lk * 4] = h;
    }

  const unsigned short* c16 = (const unsigned short*)cnt[w];
  halfv8 am[2];
#pragma unroll
  for (int mt = 0; mt < 2; ++mt) {
    const int i = mt * 16 + lr;
#pragma unroll
    for (int q = 0; q < 8; ++q) {
      const int j = lk * 8 + q;
      float c = (float)c16[i * 32 + j] + ((j == i) ? 1.f : 0.f);
      am[mt][q] = (half_t)c;
    }
  }

  floatv4 acc2[2][8] = {};
#pragma unroll
  for (int nt = 0; nt < 8; ++nt) {
    halfv8 bf = *(const halfv8*)&yw[(nt * 16 + lr) * YP + lk * 8];
#pragma unroll
    for (int mt = 0; mt < 2; ++mt)
      acc2[mt][nt] = __builtin_amdgcn_mfma_f32_16x16x32_f16(am[mt], bf,
                                                            acc2[mt][nt], 0, 0, 0);
  }
  __builtin_amdgcn_sched_barrier(0);

#pragma unroll
  for (int nt = 0; nt < 8; ++nt) {
    const float bias = gb[nt * 16 + lr];
#pragma unroll
    for (int mt = 0; mt < 2; ++mt) {
      halfv4 h;
#pragma unroll
      for (int q = 0; q < 4; ++q) {
        const float v = acc2[mt][nt][q] + bias;
        h[q] = (half_t)(v > 0.f ? v : 0.f);
      }
      *(halfv4*)&yw[(nt * 16 + lr) * YP + mt * 16 + lk * 4] = h;
    }
  }
  __builtin_amdgcn_sched_barrier(0);

  half_t* Hg = H + (size_t)g * KDIM;
#pragma unroll
  for (int c = 0; c < 8; ++c) {
    const int ch = c * 64 + l;
    const int o = ch >> 2, m0 = (ch & 3) * 8;
    halfv8 v = *(const halfv8*)&yw[o * YP + m0];
    *(halfv8*)(Hg + ch * 8) = v;
  }
}

// ---------------------------------------------------------------------------
// lin1 GEMM: half-tile pipelined (audited). LDS [2buf][2half][128][64] per
// operand (128B rows, XOR-8 both sides -> 2-way max). 4 phases/K-tile, each
// stages one half of a future tile; vmcnt(4) ONCE per tile (never 0 in loop).
// Ledger: tile T staged at (T-2).p3 [h0B], (T-2).p4 [h0A], (T-1).p1 [h1A],
// (T-1).p2 [h1B]; at T.p1 exactly 2 events (4 loads) postdate T's halves.
// WAR: each stage follows an lgkmcnt(0)+barrier postdating that region's
// last reads.
__global__ __launch_bounds__(512, 2) void lin1_gemm(
    const half_t* __restrict__ A, const half_t* __restrict__ B,
    half_t* __restrict__ Cbase) {
  __shared__ __attribute__((aligned(16))) half_t As[2 * 2 * 8192];  // 64 KB
  __shared__ __attribute__((aligned(16))) half_t Bs[2 * 2 * 8192];  // 64 KB

  const int t = threadIdx.x;
  const int orig = blockIdx.x;                     // 256 blocks, 1/CU
  const int wg = (orig & 7) * 32 + (orig >> 3);    // bijective XCD swizzle
  const int mt = wg & 15, rest = wg >> 4;
  const int nt_ = rest & 3, ksz = rest >> 2;
  const int m0 = mt * BM, n0 = nt_ * BN, k0 = ksz * KSLEN;

  const int srow0 = t >> 3, c_ = t & 7;
  const int cs0 = (c_ ^ (srow0 & 7)) * 8;
  const int srow1 = srow0 + 64;
  const int cs1 = (c_ ^ (srow1 & 7)) * 8;
  const half_t* gA[2][2] = {
      {A + (size_t)(m0 + srow0) * KDIM + k0 + cs0,
       A + (size_t)(m0 + srow1) * KDIM + k0 + cs1},
      {A + (size_t)(m0 + 128 + srow0) * KDIM + k0 + cs0,
       A + (size_t)(m0 + 128 + srow1) * KDIM + k0 + cs1}};
  const half_t* gB[2][2] = {
      {B + (size_t)(n0 + srow0) * KDIM + k0 + cs0,
       B + (size_t)(n0 + srow1) * KDIM + k0 + cs1},
      {B + (size_t)(n0 + 128 + srow0) * KDIM + k0 + cs0,
       B + (size_t)(n0 + 128 + srow1) * KDIM + k0 + cs1}};

#define STG_A(buf, hf, kk)                                                   \
  { GLDS16(gA[hf][0] + (kk) * BK, &As[(buf) * 16384 + (hf) * 8192 + t * 8]); \
    GLDS16(gA[hf][1] + (kk) * BK,                                            \
           &As[(buf) * 16384 + (hf) * 8192 + (t + 512) * 8]); }
#define STG_B(buf, hf, kk)                                                   \
  { GLDS16(gB[hf][0] + (kk) * BK, &Bs[(buf) * 16384 + (hf) * 8192 + t * 8]); \
    GLDS16(gB[hf][1] + (kk) * BK,                                            \
           &Bs[(buf) * 16384 + (hf) * 8192 + (t + 512) * 8]); }

  const int w = t >> 6, l = t & 63, lr = l & 15, lk = l >> 4;
  const int wm = (w >> 2) * 128, wn = (w & 3) * 64;
  const int ah = wm >> 7;                 // wave's A half
  const int bh = wn >> 7;                 // wave's B half
  const int bro = (wn & 64) + lr;         // B row-in-half base
  const int rsw = lr & 7;                 // row&7 for all fragment rows

  floatv4 acc[8][4] = {};

  // prologue: h0B(0) h0A(0) h1A(0) h1B(0) h0B(1) h0A(1)
  STG_B(0, 0, 0) STG_A(0, 0, 0) STG_A(0, 1, 0) STG_B(0, 1, 0)
  STG_B(1, 0, 1) STG_A(1, 0, 1)

  for (int kt = 0; kt < NT; ++kt) {
    const int cur = kt & 1, nxt = cur ^ 1;
    const int kA = (kt + 1) & 15, kB = (kt + 2) & 15;  // dummies wrap
    halfv8 af[4][2], bfA[2][2], bfB[2][2];

    // ---- p1: gate tile kt (vmcnt 4); stage h1A(kt+1); mfA x nfA
    asm volatile("s_waitcnt vmcnt(4)" ::: "memory");
    __builtin_amdgcn_s_barrier();
    __builtin_amdgcn_sched_barrier(0);
    STG_A(nxt, 1, kA)
#pragma unroll
    for (int mf = 0; mf < 4; ++mf)
#pragma unroll
      for (int ks = 0; ks < 2; ++ks)
        af[mf][ks] = *(const halfv8*)&As[cur * 16384 + ah * 8192 +
                                         (mf * 16 + lr) * 64 +
                                         (((ks * 4 + lk) ^ rsw) * 8)];
#pragma unroll
    for (int nf = 0; nf < 2; ++nf)
#pragma unroll
      for (int ks = 0; ks < 2; ++ks)
        bfA[nf][ks] = *(const halfv8*)&Bs[cur * 16384 + bh * 8192 +
                                          (bro + nf * 16) * 64 +
                                          (((ks * 4 + lk) ^ rsw) * 8)];
    __builtin_amdgcn_s_setprio(1);
#pragma unroll
    for (int mf = 0; mf < 4; ++mf)
#pragma unroll
      for (int nf = 0; nf < 2; ++nf)
#pragma unroll
        for (int ks = 0; ks < 2; ++ks)
          acc[mf][nf] = __builtin_amdgcn_mfma_f32_16x16x32_f16(
              af[mf][ks], bfA[nf][ks], acc[mf][nf], 0, 0, 0);
    __builtin_amdgcn_s_setprio(0);

    // ---- p2: stage h1B(kt+1); read bfB; mfA x nfB (no barrier)
    STG_B(nxt, 1, kA)
#pragma unroll
    for (int nf = 0; nf < 2; ++nf)
#pragma unroll
      for (int ks = 0; ks < 2; ++ks)
        bfB[nf][ks] = *(const halfv8*)&Bs[cur * 16384 + bh * 8192 +
                                          (bro + 32 + nf * 16) * 64 +
                                          (((ks * 4 + lk) ^ rsw) * 8)];
    __builtin_amdgcn_s_setprio(1);
#pragma unroll
    for (int mf = 0; mf < 4; ++mf)
#pragma unroll
      for (int nf = 0; nf < 2; ++nf)
#pragma unroll
        for (int ks = 0; ks < 2; ++ks)
          acc[mf][nf + 2] = __builtin_amdgcn_mfma_f32_16x16x32_f16(
              af[mf][ks], bfB[nf][ks], acc[mf][nf + 2], 0, 0, 0);
    __builtin_amdgcn_s_setprio(0);

    // ---- p3: B(cur) reads drained -> stage h0B(kt+2); A rows 64-127; mfB x nfA
    asm volatile("s_waitcnt lgkmcnt(0)" ::: "memory");
    __builtin_amdgcn_s_barrier();
    __builtin_amdgcn_sched_barrier(0);
    STG_B(cur, 0, kB)
#pragma unroll
    for (int mf = 0; mf < 4; ++mf)
#pragma unroll
      for (int ks = 0; ks < 2; ++ks)
        af[mf][ks] = *(const halfv8*)&As[cur * 16384 + ah * 8192 +
                                         (64 + mf * 16 + lr) * 64 +
                                         (((ks * 4 + lk) ^ rsw) * 8)];
    __builtin_amdgcn_s_setprio(1);
#pragma unroll
    for (int mf = 0; mf < 4; ++mf)
#pragma unroll
      for (int nf = 0; nf < 2; ++nf)
#pragma unroll
        for (int ks = 0; ks < 2; ++ks)
          acc[mf + 4][nf] = __builtin_amdgcn_mfma_f32_16x16x32_f16(
              af[mf][ks], bfA[nf][ks], acc[mf + 4][nf], 0, 0, 0);
    __builtin_amdgcn_s_setprio(0);

    // ---- p4: A(cur) reads drained -> stage h0A(kt+2); mfB x nfB
    asm volatile("s_waitcnt lgkmcnt(0)" ::: "memory");
    __builtin_amdgcn_s_barrier();
    __builtin_amdgcn_sched_barrier(0);
    STG_A(cur, 0, kB)
    __builtin_amdgcn_s_setprio(1);
#pragma unroll
    for (int mf = 0; mf < 4; ++mf)
#pragma unroll
      for (int nf = 0; nf < 2; ++nf)
#pragma unroll
        for (int ks = 0; ks < 2; ++ks)
          acc[mf + 4][nf + 2] = __builtin_amdgcn_mfma_f32_16x16x32_f16(
              af[mf][ks], bfB[nf][ks], acc[mf + 4][nf + 2], 0, 0, 0);
    __builtin_amdgcn_s_setprio(0);
  }

  // epilogue: fp16 partial store
  half_t* C = Cbase + (size_t)ksz * ((size_t)NBS * HID);
#pragma unroll
  for (int mf = 0; mf < 8; ++mf)
#pragma unroll
    for (int nf = 0; nf < 4; ++nf) {
      const int n = n0 + wn + nf * 16 + lr;
#pragma unroll
      for (int q = 0; q < 4; ++q) {
        const int m = m0 + wm + mf * 16 + lk * 4 + q;
        C[(size_t)m * HID + n] = (half_t)acc[mf][nf][q];
      }
    }
#undef STG_A
#undef STG_B
}

// ---------------------------------------------------------------------------
// head: hidden = relu(sum_ks C[ks] + b1); logits = hidden @ w2^T + b2; softmax
__global__ __launch_bounds__(256) void head(
    const half_t* __restrict__ Cb, const float* __restrict__ b1,
    const float* __restrict__ w2, const float* __restrict__ b2,
    float* __restrict__ out) {
  __shared__ __attribute__((aligned(16))) float w2s[NCLS * HID];
  const int t = threadIdx.x;
  {
    const floatv4* s4 = (const floatv4*)w2;
    floatv4* d4 = (floatv4*)w2s;
    for (int i = t; i < (NCLS * HID) / 4; i += 256) d4[i] = s4[i];
  }
  __syncthreads();
  const int w = t >> 6, l = t & 63;
  const int row = blockIdx.x * 4 + w;

  float r[16];
#pragma unroll
  for (int jj = 0; jj < 4; ++jj) {
    floatv4 bb = *(const floatv4*)&b1[jj * 256 + l * 4];
    float s[4] = {bb[0], bb[1], bb[2], bb[3]};
#pragma unroll
    for (int p = 0; p < KS; ++p) {
      const half_t* cp = Cb + (size_t)p * ((size_t)NBS * HID) + (size_t)row * HID;
      halfv4 u = *(const halfv4*)&cp[jj * 256 + l * 4];
#pragma unroll
      for (int q = 0; q < 4; ++q) s[q] += (float)u[q];
    }
#pragma unroll
    for (int q = 0; q < 4; ++q) r[jj * 4 + q] = s[q] > 0.f ? s[q] : 0.f;
  }
  float lg[10];
#pragma unroll
  for (int c = 0; c < NCLS; ++c) {
    float p = 0.f;
#pragma unroll
    for (int jj = 0; jj < 4; ++jj) {
      floatv4 wv = *(const floatv4*)&w2s[c * HID + jj * 256 + l * 4];
      p += r[jj * 4 + 0] * wv[0] + r[jj * 4 + 1] * wv[1] +
           r[jj * 4 + 2] * wv[2] + r[jj * 4 + 3] * wv[3];
    }
#pragma unroll
    for (int off = 32; off >= 1; off >>= 1) p += __shfl_xor(p, off);
    lg[c] = p + b2[c];
  }
  float mx = lg[0];
#pragma unroll
  for (int c = 1; c < NCLS; ++c) mx = fmaxf(mx, lg[c]);
  float sum = 0.f;
#pragma unroll
  for (int c = 0; c < NCLS; ++c) { lg[c] = __expf(lg[c] - mx); sum += lg[c]; }
  const float inv = 1.f / sum;
  float myv = 0.f;
#pragma unroll
  for (int c = 0; c < NCLS; ++c) myv = (l == c) ? lg[c] * inv : myv;
  if (l < NCLS) out[(size_t)row * NCLS + l] = myv;
}

// ---------------------------------------------------------------------------
extern "C" void kernel_launch(void* const* d_in, const int* in_sizes, int n_in,
                              void* d_out, int out_size, void* d_ws, size_t ws_size,
                              hipStream_t stream) {
  (void)in_sizes; (void)n_in; (void)out_size; (void)ws_size;
  const float* x  = (const float*)d_in[0];
  const int*   ei = (const int*)d_in[1];
  const float* gw = (const float*)d_in[2];
  const float* gb = (const float*)d_in[3];
  const float* w1 = (const float*)d_in[4];
  const float* b1 = (const float*)d_in[5];
  const float* w2 = (const float*)d_in[6];
  const float* b2 = (const float*)d_in[7];
  float* out = (float*)d_out;

  char* ws = (char*)d_ws;
  half_t* H    = (half_t*)(ws);                        // 32 MB
  half_t* C    = (half_t*)(ws + 33554432);             // KS x 8 MB = 32 MB
  half_t* w1p  = (half_t*)(ws + 67108864);             //  8 MB
  half_t* gw16 = (half_t*)(ws + 75497472);             // 32 KB

  prep_cvt <<<dim3(4112),    dim3(256), 0, stream>>>(w1, w1p, gw, gw16);
  gin_fused<<<dim3(NBS / 4), dim3(256), 0, stream>>>(x, ei, gw16, gb, H);
  lin1_gemm<<<dim3(16 * 4 * KS), dim3(512), 0, stream>>>(H, w1p, C);
  head     <<<dim3(NBS / 4), dim3(256), 0, stream>>>(C, b1, w2, b2, out);
}

// Round 13
// 86.434 us; speedup vs baseline: 1.0520x; 1.0520x over previous
//
#include <hip/hip_runtime.h>

typedef _Float16 half_t;
typedef _Float16 halfv8 __attribute__((ext_vector_type(8)));
typedef _Float16 halfv4 __attribute__((ext_vector_type(4)));
typedef float    floatv4 __attribute__((ext_vector_type(4)));
typedef unsigned int uint;
typedef uint uintv4 __attribute__((ext_vector_type(4)));

#define NODES 32
#define FIN   128
#define EPG   512
#define NBS   4096
#define ETOT  (NBS*EPG)
#define HID   1024
#define KDIM  4096          // FIN*NODES
#define NCLS  10
#define YP    36            // pitch (halves) for Z^T / H^T bounce
#define WP    140           // pitch (halves) for W in LDS

// lin1 GEMM geometry (r10-proven best: 256x256, BK=64, KS=4, 2-barrier loop)
#define BM 256
#define BN 256
#define BK 64
#define KS 4
#define KSLEN (KDIM/KS)  // 1024
#define NT (KSLEN/BK)    // 16 K-tiles

#define GLDS16(g, l)                                                        \
  __builtin_amdgcn_global_load_lds(                                         \
      (const __attribute__((address_space(1))) unsigned int*)(g),           \
      (__attribute__((address_space(3))) unsigned int*)(l), 16, 0, 0)

// ---------------------------------------------------------------------------
// prep: pure fp32->fp16 casts (H layout [g][o*32+m] matches original w1).
__global__ __launch_bounds__(256) void prep_cvt(const float* __restrict__ w1,
                                                half_t* __restrict__ w1p,
                                                const float* __restrict__ gw,
                                                half_t* __restrict__ gw16) {
  const size_t q = (size_t)blockIdx.x * 256 + threadIdx.x;  // 1052672 quads
  const float* s;
  half_t* d;
  size_t off;
  if (q < 1048576) { s = w1; d = w1p; off = q; }
  else             { s = gw; d = gw16; off = q - 1048576; }
  floatv4 v = *(const floatv4*)(s + off * 4);
  halfv4 h = {(half_t)v[0], (half_t)v[1], (half_t)v[2], (half_t)v[3]};
  *(halfv4*)(d + off * 4) = h;
}

// ---------------------------------------------------------------------------
// gin_fused v7: 2 graphs per wave, software-pipelined. Both x tiles + edges
// issue up-front (g1's HBM latency hides under g0's compute); W-stage,
// barrier, and cnt/Yt buffers amortized/reused across the two graphs.
__global__ __launch_bounds__(256, 2) void gin_fused(
    const float* __restrict__ x, const int* __restrict__ ei,
    const half_t* __restrict__ gw16, const float* __restrict__ gb,
    half_t* __restrict__ H) {
  __shared__ __attribute__((aligned(16))) half_t Ws[FIN * WP];     // 35840 B
  __shared__ __attribute__((aligned(16))) half_t Yt[4][FIN * YP];  // 36864 B
  __shared__ uint cnt[4][512];                                     //  8192 B

  const int t = threadIdx.x, w = t >> 6, l = t & 63;
  const int lr = l & 15, lk = l >> 4;
  const int g0 = blockIdx.x * 8 + w * 2;

  // (a) issue BOTH graphs' x tiles (32x128 fp32 each) -> registers
  floatv4 xr[2][2][4][2];
#pragma unroll
  for (int gi = 0; gi < 2; ++gi) {
    const float* xg = x + (size_t)(g0 + gi) * (NODES * FIN);
#pragma unroll
    for (int mt = 0; mt < 2; ++mt)
#pragma unroll
      for (int kk = 0; kk < 4; ++kk) {
        const float* p = xg + (mt * 16 + lr) * FIN + kk * 32 + lk * 8;
        xr[gi][mt][kk][0] = *(const floatv4*)p;
        xr[gi][mt][kk][1] = *(const floatv4*)(p + 4);
      }
  }

  // (b) stage W into LDS, coalesced (once per block, 8 graphs amortized)
  {
    const halfv8* gsrc = (const halfv8*)gw16;
#pragma unroll
    for (int i = 0; i < 8; ++i) {
      const int c = i * 256 + t;
      const int o = c >> 4, f8 = c & 15;
      *(halfv8*)&Ws[o * WP + f8 * 8] = gsrc[c];
    }
  }

  // (c) BOTH graphs' edges
  uintv4 es[2][4];  // [gi][{s0,s1,d0,d1}]
#pragma unroll
  for (int gi = 0; gi < 2; ++gi) {
    const int* sp = ei + (size_t)(g0 + gi) * EPG;
    const int* dp = ei + (size_t)ETOT + (size_t)(g0 + gi) * EPG;
    es[gi][0] = *(const uintv4*)(sp + l * 8);
    es[gi][1] = *(const uintv4*)(sp + l * 8 + 4);
    es[gi][2] = *(const uintv4*)(dp + l * 8);
    es[gi][3] = *(const uintv4*)(dp + l * 8 + 4);
  }

  half_t* yw = Yt[w];
  half_t* Hg0 = H + (size_t)g0 * KDIM;
  bool synced = false;

#pragma unroll
  for (int gi = 0; gi < 2; ++gi) {
    // (d) zero wave-private histogram; accumulate packed-u16 counts
    {
      uintv4* c4 = (uintv4*)cnt[w];
      uintv4 z = {0, 0, 0, 0};
      c4[l] = z;
      c4[l + 64] = z;
    }
#pragma unroll
    for (int q = 0; q < 4; ++q) {
      uint p0 = (es[gi][2][q] & 31) * 32 + (es[gi][0][q] & 31);
      atomicAdd(&cnt[w][p0 >> 1], 1u << ((p0 & 1) * 16));
      uint p1 = (es[gi][3][q] & 31) * 32 + (es[gi][1][q] & 31);
      atomicAdd(&cnt[w][p1 >> 1], 1u << ((p1 & 1) * 16));
    }

    // (e) x -> fp16 A-fragments (waits only this graph's loads)
    halfv8 af[2][4];
#pragma unroll
    for (int mt = 0; mt < 2; ++mt)
#pragma unroll
      for (int kk = 0; kk < 4; ++kk) {
        halfv8 h;
#pragma unroll
        for (int q = 0; q < 4; ++q) {
          h[q]     = (half_t)xr[gi][mt][kk][0][q];
          h[q + 4] = (half_t)xr[gi][mt][kk][1][q];
        }
        af[mt][kk] = h;
      }

    if (!synced) { __syncthreads(); synced = true; }  // Ws staged (cross-wave)

    // (f) MFMA1: Z[j][o] = sum_f x[j][f] W[o][f]; W frags from LDS
    floatv4 acc[2][8] = {};
#pragma unroll
    for (int kk = 0; kk < 4; ++kk) {
      halfv8 bfk[8];
#pragma unroll
      for (int nt = 0; nt < 8; ++nt)
        bfk[nt] = *(const halfv8*)&Ws[(nt * 16 + lr) * WP + kk * 32 + lk * 8];
#pragma unroll
      for (int nt = 0; nt < 8; ++nt)
#pragma unroll
        for (int mt = 0; mt < 2; ++mt)
          acc[mt][nt] = __builtin_amdgcn_mfma_f32_16x16x32_f16(
              af[mt][kk], bfk[nt], acc[mt][nt], 0, 0, 0);
    }
    __builtin_amdgcn_sched_barrier(0);  // (g1: also orders after g0's Yt reads)

    // (g) bounce Z^T into this wave's LDS: Yt[o][j]
#pragma unroll
    for (int mt = 0; mt < 2; ++mt)
#pragma unroll
      for (int nt = 0; nt < 8; ++nt) {
        halfv4 h = {(half_t)acc[mt][nt][0], (half_t)acc[mt][nt][1],
                    (half_t)acc[mt][nt][2], (half_t)acc[mt][nt][3]};
        *(halfv4*)&yw[(nt * 16 + lr) * YP + mt * 16 + lk * 4] = h;
      }

    // (h) M' = I + C fragments from histogram
    const unsigned short* c16 = (const unsigned short*)cnt[w];
    halfv8 am[2];
#pragma unroll
    for (int mt = 0; mt < 2; ++mt) {
      const int i = mt * 16 + lr;
#pragma unroll
      for (int q = 0; q < 8; ++q) {
        const int j = lk * 8 + q;
        float c = (float)c16[i * 32 + j] + ((j == i) ? 1.f : 0.f);
        am[mt][q] = (half_t)c;
      }
    }

    // (i) MFMA2: H[i][o] = sum_j M'[i][j] Z[j][o]
    floatv4 acc2[2][8] = {};
#pragma unroll
    for (int nt = 0; nt < 8; ++nt) {
      halfv8 bf = *(const halfv8*)&yw[(nt * 16 + lr) * YP + lk * 8];
#pragma unroll
      for (int mt = 0; mt < 2; ++mt)
        acc2[mt][nt] = __builtin_amdgcn_mfma_f32_16x16x32_f16(
            am[mt], bf, acc2[mt][nt], 0, 0, 0);
    }
    __builtin_amdgcn_sched_barrier(0);  // keep H^T writes below all Z^T reads

    // (j) bias + relu; overwrite buffer with H^T[o][m]
#pragma unroll
    for (int nt = 0; nt < 8; ++nt) {
      const float bias = gb[nt * 16 + lr];
#pragma unroll
      for (int mt = 0; mt < 2; ++mt) {
        halfv4 h;
#pragma unroll
        for (int q = 0; q < 4; ++q) {
          const float v = acc2[mt][nt][q] + bias;
          h[q] = (half_t)(v > 0.f ? v : 0.f);
        }
        *(halfv4*)&yw[(nt * 16 + lr) * YP + mt * 16 + lk * 4] = h;
      }
    }
    __builtin_amdgcn_sched_barrier(0);

    // (k) linear readback -> fat coalesced stores: H[g][o*32+m], 1KB/instr
    half_t* Hg = Hg0 + (size_t)gi * KDIM;
#pragma unroll
    for (int c = 0; c < 8; ++c) {
      const int ch = c * 64 + l;
      const int o = ch >> 2, m0 = (ch & 3) * 8;
      halfv8 v = *(const halfv8*)&yw[o * YP + m0];
      *(halfv8*)(Hg + ch * 8) = v;
    }
  }
}

// ---------------------------------------------------------------------------
// lin1 GEMM (r10-proven, 45.5 us): 256x256 tile, BK=64 (128B rows), 8 waves,
// split-K=4, XOR-8 chunk swizzle (0 conflicts), 2-barrier K-loop,
// counted vmcnt(8) with 1-tile lookahead.
__global__ __launch_bounds__(512, 2) void lin1_gemm(
    const half_t* __restrict__ A, const half_t* __restrict__ B,
    half_t* __restrict__ Cbase) {
  __shared__ __attribute__((aligned(16))) half_t As[2][BM * BK];  // 64 KB
  __shared__ __attribute__((aligned(16))) half_t Bs[2][BN * BK];  // 64 KB

  const int t = threadIdx.x;
  const int orig = blockIdx.x;
  const int wg = (orig & 7) * 32 + (orig >> 3);    // bijective XCD swizzle
  const int mt = wg & 15, rest = wg >> 4;
  const int nt_ = rest & 3, ks = rest >> 2;
  const int m0 = mt * BM, n0 = nt_ * BN, k0 = ks * KSLEN;

  const half_t* gA[4];
  const half_t* gB[4];
#pragma unroll
  for (int j = 0; j < 4; ++j) {
    const int L = t + j * 512;
    const int r = L >> 3;
    const int c = (L & 7) ^ (r & 7);
    gA[j] = A + (size_t)(m0 + r) * KDIM + k0 + c * 8;
    gB[j] = B + (size_t)(n0 + r) * KDIM + k0 + c * 8;
  }

#define STAGE(buf, koff)                                                    \
  {                                                                         \
    _Pragma("unroll")                                                       \
    for (int j = 0; j < 4; ++j)                                             \
      GLDS16(gA[j] + (koff), &As[buf][(t + j * 512) * 8]);                  \
    _Pragma("unroll")                                                       \
    for (int j = 0; j < 4; ++j)                                             \
      GLDS16(gB[j] + (koff), &Bs[buf][(t + j * 512) * 8]);                  \
  }

  const int w = t >> 6, l = t & 63, lr = l & 15, lk = l >> 4;
  const int wm = (w >> 2) * 128, wn = (w & 3) * 64;

  floatv4 acc[8][4] = {};

  STAGE(0, 0)
  STAGE(1, BK)
  asm volatile("s_waitcnt vmcnt(8)" ::: "memory");
  __builtin_amdgcn_s_barrier();

  for (int kt = 0; kt < NT; ++kt) {
    const int cur = kt & 1;
    const half_t* as = As[cur];
    const half_t* bs = Bs[cur];
#pragma unroll
    for (int ksb = 0; ksb < 2; ++ksb) {
      halfv8 bf[4], af[8];
#pragma unroll
      for (int nf = 0; nf < 4; ++nf) {
        const int row = wn + nf * 16 + lr;
        const int ch = (ksb * 4 + lk) ^ (row & 7);
        bf[nf] = *(const halfv8*)&bs[row * BK + ch * 8];
      }
#pragma unroll
      for (int mf = 0; mf < 8; ++mf) {
        const int row = wm + mf * 16 + lr;
        const int ch = (ksb * 4 + lk) ^ (row & 7);
        af[mf] = *(const halfv8*)&as[row * BK + ch * 8];
      }
      __builtin_amdgcn_s_setprio(1);
#pragma unroll
      for (int mf = 0; mf < 8; ++mf)
#pragma unroll
        for (int nf = 0; nf < 4; ++nf)
          acc[mf][nf] = __builtin_amdgcn_mfma_f32_16x16x32_f16(
              af[mf], bf[nf], acc[mf][nf], 0, 0, 0);
      __builtin_amdgcn_s_setprio(0);
    }
    __builtin_amdgcn_s_barrier();
    const int src = (kt + 2 < NT) ? (kt + 2) : 0;  // dummy keeps vmcnt uniform
    STAGE(cur, src * BK)
    asm volatile("s_waitcnt vmcnt(8)" ::: "memory");
    __builtin_amdgcn_s_barrier();
  }

  half_t* C = Cbase + (size_t)ks * ((size_t)NBS * HID);
#pragma unroll
  for (int mf = 0; mf < 8; ++mf)
#pragma unroll
    for (int nf = 0; nf < 4; ++nf) {
      const int n = n0 + wn + nf * 16 + lr;
#pragma unroll
      for (int q = 0; q < 4; ++q) {
        const int m = m0 + wm + mf * 16 + lk * 4 + q;
        C[(size_t)m * HID + n] = (half_t)acc[mf][nf][q];
      }
    }
#undef STAGE
}

// ---------------------------------------------------------------------------
// head: hidden = relu(sum_ks C[ks] + b1); logits = hidden @ w2^T + b2; softmax
__global__ __launch_bounds__(256) void head(
    const half_t* __restrict__ Cb, const float* __restrict__ b1,
    const float* __restrict__ w2, const float* __restrict__ b2,
    float* __restrict__ out) {
  __shared__ __attribute__((aligned(16))) float w2s[NCLS * HID];
  const int t = threadIdx.x;
  {
    const floatv4* s4 = (const floatv4*)w2;
    floatv4* d4 = (floatv4*)w2s;
    for (int i = t; i < (NCLS * HID) / 4; i += 256) d4[i] = s4[i];
  }
  __syncthreads();
  const int w = t >> 6, l = t & 63;
  const int row = blockIdx.x * 4 + w;

  float r[16];
#pragma unroll
  for (int jj = 0; jj < 4; ++jj) {
    floatv4 bb = *(const floatv4*)&b1[jj * 256 + l * 4];
    float s[4] = {bb[0], bb[1], bb[2], bb[3]};
#pragma unroll
    for (int p = 0; p < KS; ++p) {
      const half_t* cp = Cb + (size_t)p * ((size_t)NBS * HID) + (size_t)row * HID;
      halfv4 u = *(const halfv4*)&cp[jj * 256 + l * 4];
#pragma unroll
      for (int q = 0; q < 4; ++q) s[q] += (float)u[q];
    }
#pragma unroll
    for (int q = 0; q < 4; ++q) r[jj * 4 + q] = s[q] > 0.f ? s[q] : 0.f;
  }
  float lg[10];
#pragma unroll
  for (int c = 0; c < NCLS; ++c) {
    float p = 0.f;
#pragma unroll
    for (int jj = 0; jj < 4; ++jj) {
      floatv4 wv = *(const floatv4*)&w2s[c * HID + jj * 256 + l * 4];
      p += r[jj * 4 + 0] * wv[0] + r[jj * 4 + 1] * wv[1] +
           r[jj * 4 + 2] * wv[2] + r[jj * 4 + 3] * wv[3];
    }
#pragma unroll
    for (int off = 32; off >= 1; off >>= 1) p += __shfl_xor(p, off);
    lg[c] = p + b2[c];
  }
  float mx = lg[0];
#pragma unroll
  for (int c = 1; c < NCLS; ++c) mx = fmaxf(mx, lg[c]);
  float sum = 0.f;
#pragma unroll
  for (int c = 0; c < NCLS; ++c) { lg[c] = __expf(lg[c] - mx); sum += lg[c]; }
  const float inv = 1.f / sum;
  float myv = 0.f;
#pragma unroll
  for (int c = 0; c < NCLS; ++c) myv = (l == c) ? lg[c] * inv : myv;
  if (l < NCLS) out[(size_t)row * NCLS + l] = myv;
}

// ---------------------------------------------------------------------------
extern "C" void kernel_launch(void* const* d_in, const int* in_sizes, int n_in,
                              void* d_out, int out_size, void* d_ws, size_t ws_size,
                              hipStream_t stream) {
  (void)in_sizes; (void)n_in; (void)out_size; (void)ws_size;
  const float* x  = (const float*)d_in[0];
  const int*   ei = (const int*)d_in[1];
  const float* gw = (const float*)d_in[2];
  const float* gb = (const float*)d_in[3];
  const float* w1 = (const float*)d_in[4];
  const float* b1 = (const float*)d_in[5];
  const float* w2 = (const float*)d_in[6];
  const float* b2 = (const float*)d_in[7];
  float* out = (float*)d_out;

  char* ws = (char*)d_ws;
  half_t* H    = (half_t*)(ws);                        // 32 MB
  half_t* C    = (half_t*)(ws + 33554432);             // KS x 8 MB = 32 MB
  half_t* w1p  = (half_t*)(ws + 67108864);             //  8 MB
  half_t* gw16 = (half_t*)(ws + 75497472);             // 32 KB

  prep_cvt <<<dim3(4112),    dim3(256), 0, stream>>>(w1, w1p, gw, gw16);
  gin_fused<<<dim3(NBS / 8), dim3(256), 0, stream>>>(x, ei, gw16, gb, H);
  lin1_gemm<<<dim3(16 * 4 * KS), dim3(512), 0, stream>>>(H, w1p, C);
  head     <<<dim3(NBS / 4), dim3(256), 0, stream>>>(C, b1, w2, b2, out);
}